// Round 12
// baseline (161.511 us; speedup 1.0000x reference)
//
#include <hip/hip_runtime.h>
#include <hip/hip_bf16.h>

#define N_NODES 50000
#define N_EDGES 800000
#define D 256
#define DEPTH 10
#define PAD_CAP 48
#define SENTINEL 50000
#define NG ((N_NODES + 255) / 256)    // 196
#define NGZ 49                        // ceil(50048/4/256): int4 cnt-zero blocks
#define NCHUNK 9
#define CHUNK_E ((N_EDGES + NCHUNK - 1) / NCHUNK)        // 88889
#define CHUNK_BLKS ((CHUNK_E + 255) / 256)               // 348

// ws layout (4-byte units):
//   cnt[50048], slots[N_NODES*PAD_CAP], uA[256], uB[256], cbuf[16],
//   ya[50048], yb[50048], ng4[50048]

// ---------- combo: one chain matvec step + (cnt-zero | scatter chunk) ----------
// blocks 0..63 : row r = blk*4 + wave; lanes hold W[r][lane*4..+3] (coalesced 1KB);
//                one load round per row, 6-shfl reduce, lane0 stores uout[r].
//                (uin written by the PREVIOUS launch -> kernel boundary orders it)
// block 64     : *cout = bsrow . uin   (wave 0)
// blocks 65..  : ecount==0 -> zero cnt via int4 ; else scatter edges [ebase, ebase+ecount)
__global__ __launch_bounds__(256) void combo_kernel(
    const float* __restrict__ W, const float* __restrict__ bsrow,
    const float* __restrict__ uin, float* __restrict__ uout, float* __restrict__ cout,
    int* __restrict__ cnt, const int* __restrict__ src, const int* __restrict__ dst,
    int* __restrict__ slots, int ebase, int ecount)
{
    const int b = blockIdx.x, t = threadIdx.x;
    if (b < 64) {
        const int wave = t >> 6, lane = t & 63;
        const int r = b * 4 + wave;
        float4 w4 = *reinterpret_cast<const float4*>(W + (size_t)r * D + lane * 4);
        float4 u4 = *reinterpret_cast<const float4*>(uin + lane * 4);
        float p = w4.x * u4.x + w4.y * u4.y + w4.z * u4.z + w4.w * u4.w;
        for (int off = 32; off > 0; off >>= 1) p += __shfl_down(p, off);
        if (lane == 0) uout[r] = p;
    } else if (b == 64) {
        if (t < 64) {
            float4 b4 = *reinterpret_cast<const float4*>(bsrow + t * 4);
            float4 u4 = *reinterpret_cast<const float4*>(uin + t * 4);
            float p = b4.x * u4.x + b4.y * u4.y + b4.z * u4.z + b4.w * u4.w;
            for (int off = 32; off > 0; off >>= 1) p += __shfl_down(p, off);
            if (t == 0) *cout = p;
        }
    } else if (ecount == 0) {                      // launch 0: zero cnt (int4)
        const int i = (b - 65) * 256 + t;          // 12512 int4s cover 50048 ints
        if (i < 12512) reinterpret_cast<int4*>(cnt)[i] = make_int4(0, 0, 0, 0);
    } else {                                       // launches 1..9: scatter chunk
        const int e = ebase + (b - 65) * 256 + t;
        if (e < ebase + ecount) {
            const int d = dst[e];
            const int pos = atomicAdd(&cnt[d], 1);
            if (pos < PAD_CAP) slots[(size_t)d * PAD_CAP + pos] = src[e];
        }
    }
}

// ---------- y0 + slot-row sentinel fixup + ng4 emit ----------
__global__ __launch_bounds__(256) void y0_kernel(const float* __restrict__ feat,
                                                 const int* __restrict__ cnt,
                                                 int* __restrict__ slots,
                                                 const float* __restrict__ W_in,
                                                 const float* __restrict__ b_in,
                                                 const float* __restrict__ u0v,
                                                 float* __restrict__ ya,
                                                 float* __restrict__ yb,
                                                 int* __restrict__ ng4) {
    __shared__ float Wsh[6 * D];
    __shared__ float bsh[D];
    __shared__ float ush[D];
    const int t = threadIdx.x;
    for (int i = t; i < 6 * D; i += 256) Wsh[i] = W_in[i];
    bsh[t] = b_in[t];
    ush[t] = u0v[t];
    __syncthreads();
    if (blockIdx.x == 0 && t < PAD_CAP) {   // zero the sentinel target in both buffers
        ya[SENTINEL + t] = 0.f;
        yb[SENTINEL + t] = 0.f;
    }
    const int node = blockIdx.x * 256 + t;
    if (node >= N_NODES) return;
    int c = cnt[node]; if (c > PAD_CAP) c = PAD_CAP;
    int* sl = slots + (size_t)node * PAD_CAP;
    const int cr = (c + 3) & ~3;            // pad row to multiple of 4 with SENTINEL
    for (int i = c; i < cr; ++i) sl[i] = SENTINEL;
    ng4[node] = cr >> 2;                    // packed group count for the prop sweeps
    float f0 = 0, f1 = 0, f2 = 0, f3 = 0, f4 = 0, f5 = 0;
    for (int jj = 0; jj < c; ++jj) {
        const float* fr = feat + (size_t)sl[jj] * 6;
        float2 a  = *reinterpret_cast<const float2*>(fr);
        float2 b2 = *reinterpret_cast<const float2*>(fr + 2);
        float2 cc = *reinterpret_cast<const float2*>(fr + 4);
        f0 += a.x; f1 += a.y; f2 += b2.x; f3 += b2.y; f4 += cc.x; f5 += cc.y;
    }
    float s = 0.f;
#pragma unroll 4
    for (int d2 = 0; d2 < D; ++d2) {
        float pre = bsh[d2]
                  + f0 * Wsh[d2]       + f1 * Wsh[256 + d2]  + f2 * Wsh[512 + d2]
                  + f3 * Wsh[768 + d2] + f4 * Wsh[1024 + d2] + f5 * Wsh[1280 + d2];
        s += fmaxf(pre, 0.f) * ush[d2];
    }
    ya[node] = s;
}

// ---------- prop: 4 threads/node, branch-free int4 groups, ng4 counts ----------
__global__ __launch_bounds__(256) void prop4_kernel(const float* __restrict__ yin,
                                                    float* __restrict__ yout,
                                                    const int* __restrict__ ng4,
                                                    const int* __restrict__ slots,
                                                    const float* __restrict__ cptr) {
    const int gid = blockIdx.x * 256 + threadIdx.x;
    const int node = gid >> 2, lane4 = gid & 3;
    if (node >= N_NODES) return;
    const int g4r = ng4[node];
    const int4* sl = reinterpret_cast<const int4*>(slots + (size_t)node * PAD_CAP);
    float p = 0.f;
    for (int g = lane4; g < g4r; g += 4) {
        int4 v = sl[g];
        p += yin[v.x] + yin[v.y] + yin[v.z] + yin[v.w];
    }
    p += __shfl_xor(p, 1);
    p += __shfl_xor(p, 2);
    if (lane4 == 0) yout[node] = cptr[0] + p;
}

// ---------------- launch ----------------

extern "C" void kernel_launch(void* const* d_in, const int* in_sizes, int n_in,
                              void* d_out, int out_size, void* d_ws, size_t ws_size,
                              hipStream_t stream) {
    const float* feat  = (const float*)d_in[0];
    const int*   src   = (const int*)d_in[1];
    const int*   dst   = (const int*)d_in[2];
    const float* W_in  = (const float*)d_in[3];
    const float* b_in  = (const float*)d_in[4];
    const float* Ws    = (const float*)d_in[5];
    const float* bsv   = (const float*)d_in[6];
    const float* W_out = (const float*)d_in[7];
    const float* b_out = (const float*)d_in[8];
    float* out = (float*)d_out;

    int*   cnt   = (int*)d_ws;                                   // 50048 (16B-aligned)
    int*   slots = cnt + 50048;                                  // 50000*48 (16B-aligned)
    float* uA    = (float*)(slots + (size_t)N_NODES * PAD_CAP);  // 256
    float* uB    = uA + 256;                                     // 256
    float* cbuf  = uB + 256;                                     // 16
    float* ya    = cbuf + 16;                                    // 50048
    float* yb    = ya + 50048;                                   // 50048
    int*   ng4   = (int*)(yb + 50048);                           // 50048

    const int B = 256;
    const int PG = (4 * N_NODES + B - 1) / B;        // 782

    // ---- 10 combo launches: chain step s rides with cnt-zero (s=0) or scatter chunk s-1
    // chain: u_10 = W_out; step s (layer j=10-s): u_{j-1} = Ws[j-1]@u_j, c_j = bs[j-1].u_j
    // step s writes uA if s even, uB if s odd -> u_0 ends in uB.
    {
        const float* uin = W_out;
        for (int s = 0; s < DEPTH; ++s) {
            const int j = DEPTH - s;
            float* uout = (s & 1) ? uB : uA;
            int ebase = 0, ecount = 0, grid = 65 + NGZ;          // launch 0: zero cnt
            if (s >= 1) {
                ebase  = (s - 1) * CHUNK_E;
                ecount = (s == NCHUNK) ? (N_EDGES - ebase) : CHUNK_E;
                grid   = 65 + CHUNK_BLKS;
            }
            combo_kernel<<<grid, B, 0, stream>>>(
                Ws + (size_t)(j - 1) * D * D, bsv + (size_t)(j - 1) * D,
                uin, uout, cbuf + j, cnt, src, dst, slots, ebase, ecount);
            uin = uout;
        }
    }

    y0_kernel<<<NG, B, 0, stream>>>(feat, cnt, slots, W_in, b_in, uB, ya, yb, ng4);

    float* cur = ya;
    float* nxt = yb;
    for (int k = 1; k <= DEPTH; ++k) {
        prop4_kernel<<<PG, B, 0, stream>>>(cur, nxt, ng4, slots, cbuf + k);
        float* tmp = cur; cur = nxt; nxt = tmp;
    }
    prop4_kernel<<<PG, B, 0, stream>>>(cur, out, ng4, slots, b_out);
}